// Round 1
// baseline (1377.325 us; speedup 1.0000x reference)
//
#include <hip/hip_runtime.h>
#include <hip/hip_bf16.h>
#include <math.h>

#define NN 100000
#define EE 1600000
#define FIN 256
#define HID 64
#define NC 40

// ---- degree: deg[col[e]] += w[e] ----
__global__ void deg_kernel(const int* __restrict__ col, const float* __restrict__ w,
                           float* __restrict__ deg) {
    int e = blockIdx.x * blockDim.x + threadIdx.x;
    if (e < EE) atomicAdd(&deg[col[e]], w[e]);
}

// ---- dis[i] = rsqrt(deg[i] + 1)  (self-loop weight 1; deg>=1 so always >0) ----
__global__ void dis_kernel(const float* __restrict__ deg, float* __restrict__ dis) {
    int i = blockIdx.x * blockDim.x + threadIdx.x;
    if (i < NN) dis[i] = rsqrtf(deg[i] + 1.0f);
}

// ---- GEMM1: xw[N,64] = x[N,256] @ W1[256,64].  W1 in LDS (64KB). ----
__global__ __launch_bounds__(256) void gemm1_kernel(const float* __restrict__ x,
                                                    const float* __restrict__ W,
                                                    float* __restrict__ xw) {
    __shared__ float Ws[FIN * HID];
    for (int i = threadIdx.x; i < FIN * HID; i += 256) Ws[i] = W[i];
    __syncthreads();
    int j = threadIdx.x & 63;
    int r = blockIdx.x * 4 + (threadIdx.x >> 6);
    if (r >= NN) return;
    const float* xr = x + (size_t)r * FIN;
    float acc = 0.f;
#pragma unroll 4
    for (int k = 0; k < FIN; k += 4) {
        float4 xv = *(const float4*)(xr + k);
        acc += xv.x * Ws[(k + 0) * HID + j];
        acc += xv.y * Ws[(k + 1) * HID + j];
        acc += xv.z * Ws[(k + 2) * HID + j];
        acc += xv.w * Ws[(k + 3) * HID + j];
    }
    xw[(size_t)r * HID + j] = acc;
}

// ---- scatter1: agg1[col[e],f] += norm_e * xw[row[e],f], one wave per edge ----
__global__ __launch_bounds__(256) void scatter1_kernel(const int* __restrict__ row,
                                                       const int* __restrict__ col,
                                                       const float* __restrict__ w,
                                                       const float* __restrict__ dis,
                                                       const float* __restrict__ xw,
                                                       float* __restrict__ agg) {
    int e = blockIdx.x * 4 + (threadIdx.x >> 6);
    if (e >= EE) return;
    int lane = threadIdx.x & 63;
    int r = row[e], c = col[e];
    float nrm = dis[r] * w[e] * dis[c];
    atomicAdd(&agg[(size_t)c * HID + lane], nrm * xw[(size_t)r * HID + lane]);
}

// ---- h = relu(agg1 + dis^2 * xw + b1)  (self-loop folded in), in-place over agg1 ----
__global__ void relu_kernel(float* __restrict__ agg, const float* __restrict__ xw,
                            const float* __restrict__ dis, const float* __restrict__ b) {
    int i = blockIdx.x * blockDim.x + threadIdx.x;
    if (i >= NN * HID) return;
    int r = i >> 6;
    int f = i & 63;
    float d = dis[r];
    agg[i] = fmaxf(agg[i] + d * d * xw[i] + b[f], 0.f);
}

// ---- GEMM2: hw2[N,40] = h[N,64] @ W2[64,40] ----
__global__ __launch_bounds__(256) void gemm2_kernel(const float* __restrict__ h,
                                                    const float* __restrict__ W,
                                                    float* __restrict__ hw) {
    __shared__ float Ws[HID * NC];
    for (int i = threadIdx.x; i < HID * NC; i += 256) Ws[i] = W[i];
    __syncthreads();
    int j = threadIdx.x & 63;
    int r = blockIdx.x * 4 + (threadIdx.x >> 6);
    if (r >= NN || j >= NC) return;
    const float* hr = h + (size_t)r * HID;
    float acc = 0.f;
#pragma unroll 4
    for (int k = 0; k < HID; k += 4) {
        float4 hv = *(const float4*)(hr + k);
        acc += hv.x * Ws[(k + 0) * NC + j];
        acc += hv.y * Ws[(k + 1) * NC + j];
        acc += hv.z * Ws[(k + 2) * NC + j];
        acc += hv.w * Ws[(k + 3) * NC + j];
    }
    hw[(size_t)r * NC + j] = acc;
}

// ---- scatter2: agg2[col[e],f] += norm_e * hw2[row[e],f], 40 active lanes/edge ----
__global__ __launch_bounds__(256) void scatter2_kernel(const int* __restrict__ row,
                                                       const int* __restrict__ col,
                                                       const float* __restrict__ w,
                                                       const float* __restrict__ dis,
                                                       const float* __restrict__ hw,
                                                       float* __restrict__ agg) {
    int e = blockIdx.x * 4 + (threadIdx.x >> 6);
    if (e >= EE) return;
    int lane = threadIdx.x & 63;
    if (lane >= NC) return;
    int r = row[e], c = col[e];
    float nrm = dis[r] * w[e] * dis[c];
    atomicAdd(&agg[(size_t)c * NC + lane], nrm * hw[(size_t)r * NC + lane]);
}

// ---- final: out = agg2 + dis^2*hw2 + b2 ; log_softmax via wave shuffles ----
__global__ __launch_bounds__(256) void final_kernel(const float* __restrict__ agg,
                                                    const float* __restrict__ hw,
                                                    const float* __restrict__ dis,
                                                    const float* __restrict__ b,
                                                    float* __restrict__ out) {
    int lane = threadIdx.x & 63;
    int r = blockIdx.x * 4 + (threadIdx.x >> 6);
    if (r >= NN) return;
    float val = 0.f;
    float v = -INFINITY;
    if (lane < NC) {
        float d = dis[r];
        size_t idx = (size_t)r * NC + lane;
        val = agg[idx] + d * d * hw[idx] + b[lane];
        v = val;
    }
    float m = v;
#pragma unroll
    for (int off = 32; off; off >>= 1) m = fmaxf(m, __shfl_xor(m, off));
    float e = (lane < NC) ? expf(val - m) : 0.f;
    float s = e;
#pragma unroll
    for (int off = 32; off; off >>= 1) s += __shfl_xor(s, off);
    float lse = m + logf(s);
    if (lane < NC) {
        size_t idx = (size_t)r * NC + lane;
        out[idx] = val;
        out[(size_t)NN * NC + idx] = val - lse;
    }
}

extern "C" void kernel_launch(void* const* d_in, const int* in_sizes, int n_in,
                              void* d_out, int out_size, void* d_ws, size_t ws_size,
                              hipStream_t stream) {
    const float* x    = (const float*)d_in[0];
    const int*   eidx = (const int*)d_in[1];   // [2, E] int32
    const float* ew   = (const float*)d_in[2];
    const float* W1   = (const float*)d_in[3];
    const float* b1   = (const float*)d_in[4];
    const float* W2   = (const float*)d_in[5];
    const float* b2   = (const float*)d_in[6];
    float* out = (float*)d_out;

    const int* row = eidx;        // edge_index[0]
    const int* col = eidx + EE;   // edge_index[1]

    float* ws   = (float*)d_ws;
    float* deg  = ws;                    // N
    float* dis  = deg + NN;              // N
    float* xw   = dis + NN;              // N*64
    float* agg1 = xw + (size_t)NN * HID; // N*64  (becomes h after relu)
    float* hw2  = agg1 + (size_t)NN * HID; // N*40
    float* agg2 = hw2 + (size_t)NN * NC;   // N*40

    hipMemsetAsync(deg, 0, NN * sizeof(float), stream);
    hipMemsetAsync(agg1, 0, (size_t)NN * HID * sizeof(float), stream);
    hipMemsetAsync(agg2, 0, (size_t)NN * NC * sizeof(float), stream);

    deg_kernel<<<(EE + 255) / 256, 256, 0, stream>>>(col, ew, deg);
    dis_kernel<<<(NN + 255) / 256, 256, 0, stream>>>(deg, dis);
    gemm1_kernel<<<(NN + 3) / 4, 256, 0, stream>>>(x, W1, xw);
    scatter1_kernel<<<(EE + 3) / 4, 256, 0, stream>>>(row, col, ew, dis, xw, agg1);
    relu_kernel<<<(NN * HID + 255) / 256, 256, 0, stream>>>(agg1, xw, dis, b1);
    gemm2_kernel<<<(NN + 3) / 4, 256, 0, stream>>>(agg1, W2, hw2);
    scatter2_kernel<<<(EE + 3) / 4, 256, 0, stream>>>(row, col, ew, dis, hw2, agg2);
    final_kernel<<<(NN + 3) / 4, 256, 0, stream>>>(agg2, hw2, dis, b2, out);
}

// Round 2
// 980.737 us; speedup vs baseline: 1.4044x; 1.4044x over previous
//
#include <hip/hip_runtime.h>
#include <hip/hip_bf16.h>
#include <math.h>

#define NN 100000
#define EE 1600000
#define FIN 256
#define HID 64
#define NC 40

// ---- degree: deg[col[e]] += w[e] ----
__global__ void deg_kernel(const int* __restrict__ col, const float* __restrict__ w,
                           float* __restrict__ deg) {
    int e = blockIdx.x * blockDim.x + threadIdx.x;
    if (e < EE) atomicAdd(&deg[col[e]], w[e]);
}

// ---- dis[i] = rsqrt(deg[i] + 1)  (self-loop weight 1; deg+1 always > 0) ----
__global__ void dis_kernel(const float* __restrict__ deg, float* __restrict__ dis) {
    int i = blockIdx.x * blockDim.x + threadIdx.x;
    if (i < NN) dis[i] = rsqrtf(deg[i] + 1.0f);
}

// ---- GEMM1: xw[N,64] = x[N,256] @ W1[256,64]. 64-row tile, 4x4 micro-tile ----
__global__ __launch_bounds__(256) void gemm1_kernel(const float* __restrict__ x,
                                                    const float* __restrict__ W,
                                                    float* __restrict__ xw) {
    __shared__ float xs[64][65];   // [row][k] in tile; pad 1 -> broadcast-free reads
    __shared__ float Ws[64][72];   // [k][col] in tile; pad 8 keeps 16B align, 2-way max
    const int tid = threadIdx.x;
    const int base = blockIdx.x * 64;
    const int ty = tid >> 4;       // 0..15 -> rows ty*4 .. ty*4+3
    const int tx = tid & 15;       // cols tx*4 .. tx*4+3
    float acc[4][4] = {};

    for (int kb = 0; kb < FIN; kb += 64) {
        // stage x tile: 64 rows x 64 k (coalesced float4)
        for (int v = tid; v < 1024; v += 256) {
            int r = v >> 4, q = v & 15;
            int gr = base + r;
            float4 xv = make_float4(0.f, 0.f, 0.f, 0.f);
            if (gr < NN) xv = *(const float4*)(x + (size_t)gr * FIN + kb + q * 4);
            xs[r][q * 4 + 0] = xv.x; xs[r][q * 4 + 1] = xv.y;
            xs[r][q * 4 + 2] = xv.z; xs[r][q * 4 + 3] = xv.w;
        }
        // stage W tile: 64 k x 64 cols
        for (int v = tid; v < 1024; v += 256) {
            int k = v >> 4, q = v & 15;
            float4 wv = *(const float4*)(W + (size_t)(kb + k) * HID + q * 4);
            *(float4*)(&Ws[k][q * 4]) = wv;
        }
        __syncthreads();
#pragma unroll 8
        for (int k = 0; k < 64; k++) {
            float4 wv = *(const float4*)(&Ws[k][tx * 4]);
            float x0 = xs[ty * 4 + 0][k];
            float x1 = xs[ty * 4 + 1][k];
            float x2 = xs[ty * 4 + 2][k];
            float x3 = xs[ty * 4 + 3][k];
            acc[0][0] += x0 * wv.x; acc[0][1] += x0 * wv.y; acc[0][2] += x0 * wv.z; acc[0][3] += x0 * wv.w;
            acc[1][0] += x1 * wv.x; acc[1][1] += x1 * wv.y; acc[1][2] += x1 * wv.z; acc[1][3] += x1 * wv.w;
            acc[2][0] += x2 * wv.x; acc[2][1] += x2 * wv.y; acc[2][2] += x2 * wv.z; acc[2][3] += x2 * wv.w;
            acc[3][0] += x3 * wv.x; acc[3][1] += x3 * wv.y; acc[3][2] += x3 * wv.z; acc[3][3] += x3 * wv.w;
        }
        __syncthreads();
    }
#pragma unroll
    for (int i = 0; i < 4; i++) {
        int gr = base + ty * 4 + i;
        if (gr < NN)
            *(float4*)(xw + (size_t)gr * HID + tx * 4) =
                make_float4(acc[i][0], acc[i][1], acc[i][2], acc[i][3]);
    }
}

// ---- scatter1: agg1[col[e],f] += norm_e * xw[row[e],f], one wave per edge ----
__global__ __launch_bounds__(256) void scatter1_kernel(const int* __restrict__ row,
                                                       const int* __restrict__ col,
                                                       const float* __restrict__ w,
                                                       const float* __restrict__ dis,
                                                       const float* __restrict__ xw,
                                                       float* __restrict__ agg) {
    int e = blockIdx.x * 4 + (threadIdx.x >> 6);
    if (e >= EE) return;
    int lane = threadIdx.x & 63;
    int r = row[e], c = col[e];
    float nrm = dis[r] * w[e] * dis[c];
    atomicAdd(&agg[(size_t)c * HID + lane], nrm * xw[(size_t)r * HID + lane]);
}

// ---- h = relu(agg1 + dis^2 * xw + b1), in-place over agg1 ----
__global__ void relu_kernel(float* __restrict__ agg, const float* __restrict__ xw,
                            const float* __restrict__ dis, const float* __restrict__ b) {
    int i = blockIdx.x * blockDim.x + threadIdx.x;
    if (i >= NN * HID) return;
    int r = i >> 6;
    int f = i & 63;
    float d = dis[r];
    agg[i] = fmaxf(agg[i] + d * d * xw[i] + b[f], 0.f);
}

// ---- GEMM2: hw2[N,40] = h[N,64] @ W2[64,40]. 64-row tile, 2x5 micro-tile ----
__global__ __launch_bounds__(256) void gemm2_kernel(const float* __restrict__ h,
                                                    const float* __restrict__ W,
                                                    float* __restrict__ hw) {
    __shared__ float hs[64][65];
    __shared__ float Ws[HID * NC];  // [k][col], row-major
    const int tid = threadIdx.x;
    const int base = blockIdx.x * 64;
    for (int v = tid; v < 1024; v += 256) {
        int r = v >> 4, q = v & 15;
        int gr = base + r;
        float4 hv = make_float4(0.f, 0.f, 0.f, 0.f);
        if (gr < NN) hv = *(const float4*)(h + (size_t)gr * HID + q * 4);
        hs[r][q * 4 + 0] = hv.x; hs[r][q * 4 + 1] = hv.y;
        hs[r][q * 4 + 2] = hv.z; hs[r][q * 4 + 3] = hv.w;
    }
    for (int v = tid; v < HID * NC; v += 256) Ws[v] = W[v];
    __syncthreads();
    const int tx = tid & 7;    // cols tx*5 .. tx*5+4
    const int ty = tid >> 3;   // rows ty*2, ty*2+1
    float acc[2][5] = {};
#pragma unroll 8
    for (int k = 0; k < HID; k++) {
        float h0 = hs[ty * 2 + 0][k];
        float h1 = hs[ty * 2 + 1][k];
        const float* wr = &Ws[k * NC + tx * 5];
        float w0 = wr[0], w1 = wr[1], w2 = wr[2], w3 = wr[3], w4 = wr[4];
        acc[0][0] += h0 * w0; acc[0][1] += h0 * w1; acc[0][2] += h0 * w2;
        acc[0][3] += h0 * w3; acc[0][4] += h0 * w4;
        acc[1][0] += h1 * w0; acc[1][1] += h1 * w1; acc[1][2] += h1 * w2;
        acc[1][3] += h1 * w3; acc[1][4] += h1 * w4;
    }
#pragma unroll
    for (int i = 0; i < 2; i++) {
        int gr = base + ty * 2 + i;
        if (gr < NN) {
#pragma unroll
            for (int c = 0; c < 5; c++) hw[(size_t)gr * NC + tx * 5 + c] = acc[i][c];
        }
    }
}

// ---- scatter2: agg2[col[e],f] += norm_e * hw2[row[e],f], 40 active lanes/edge ----
__global__ __launch_bounds__(256) void scatter2_kernel(const int* __restrict__ row,
                                                       const int* __restrict__ col,
                                                       const float* __restrict__ w,
                                                       const float* __restrict__ dis,
                                                       const float* __restrict__ hw,
                                                       float* __restrict__ agg) {
    int e = blockIdx.x * 4 + (threadIdx.x >> 6);
    if (e >= EE) return;
    int lane = threadIdx.x & 63;
    if (lane >= NC) return;
    int r = row[e], c = col[e];
    float nrm = dis[r] * w[e] * dis[c];
    atomicAdd(&agg[(size_t)c * NC + lane], nrm * hw[(size_t)r * NC + lane]);
}

// ---- final: out = agg2 + dis^2*hw2 + b2 ; log_softmax via wave shuffles ----
__global__ __launch_bounds__(256) void final_kernel(const float* __restrict__ agg,
                                                    const float* __restrict__ hw,
                                                    const float* __restrict__ dis,
                                                    const float* __restrict__ b,
                                                    float* __restrict__ out) {
    int lane = threadIdx.x & 63;
    int r = blockIdx.x * 4 + (threadIdx.x >> 6);
    if (r >= NN) return;
    float val = 0.f;
    float v = -INFINITY;
    if (lane < NC) {
        float d = dis[r];
        size_t idx = (size_t)r * NC + lane;
        val = agg[idx] + d * d * hw[idx] + b[lane];
        v = val;
    }
    float m = v;
#pragma unroll
    for (int off = 32; off; off >>= 1) m = fmaxf(m, __shfl_xor(m, off));
    float e = (lane < NC) ? expf(val - m) : 0.f;
    float s = e;
#pragma unroll
    for (int off = 32; off; off >>= 1) s += __shfl_xor(s, off);
    float lse = m + logf(s);
    if (lane < NC) {
        size_t idx = (size_t)r * NC + lane;
        out[idx] = val;
        out[(size_t)NN * NC + idx] = val - lse;
    }
}

extern "C" void kernel_launch(void* const* d_in, const int* in_sizes, int n_in,
                              void* d_out, int out_size, void* d_ws, size_t ws_size,
                              hipStream_t stream) {
    const float* x    = (const float*)d_in[0];
    const int*   eidx = (const int*)d_in[1];   // [2, E] int32
    const float* ew   = (const float*)d_in[2];
    const float* W1   = (const float*)d_in[3];
    const float* b1   = (const float*)d_in[4];
    const float* W2   = (const float*)d_in[5];
    const float* b2   = (const float*)d_in[6];
    float* out = (float*)d_out;

    const int* row = eidx;        // edge_index[0]
    const int* col = eidx + EE;   // edge_index[1]

    float* ws   = (float*)d_ws;
    float* deg  = ws;                      // N
    float* dis  = deg + NN;                // N
    float* xw   = dis + NN;                // N*64
    float* agg1 = xw + (size_t)NN * HID;   // N*64  (becomes h after relu)
    float* hw2  = agg1 + (size_t)NN * HID; // N*40
    float* agg2 = hw2 + (size_t)NN * NC;   // N*40

    hipMemsetAsync(deg, 0, NN * sizeof(float), stream);
    hipMemsetAsync(agg1, 0, (size_t)NN * HID * sizeof(float), stream);
    hipMemsetAsync(agg2, 0, (size_t)NN * NC * sizeof(float), stream);

    deg_kernel<<<(EE + 255) / 256, 256, 0, stream>>>(col, ew, deg);
    dis_kernel<<<(NN + 255) / 256, 256, 0, stream>>>(deg, dis);
    gemm1_kernel<<<(NN + 63) / 64, 256, 0, stream>>>(x, W1, xw);
    scatter1_kernel<<<(EE + 3) / 4, 256, 0, stream>>>(row, col, ew, dis, xw, agg1);
    relu_kernel<<<(NN * HID + 255) / 256, 256, 0, stream>>>(agg1, xw, dis, b1);
    gemm2_kernel<<<(NN + 63) / 64, 256, 0, stream>>>(agg1, W2, hw2);
    scatter2_kernel<<<(EE + 3) / 4, 256, 0, stream>>>(row, col, ew, dis, hw2, agg2);
    final_kernel<<<(NN + 3) / 4, 256, 0, stream>>>(agg2, hw2, dis, b2, out);
}

// Round 3
// 804.578 us; speedup vs baseline: 1.7119x; 1.2189x over previous
//
#include <hip/hip_runtime.h>
#include <hip/hip_bf16.h>
#include <math.h>

#define NN 100000
#define EE 1600000
#define FIN 256
#define HID 64
#define NC 40
#define NBLK 391   // ceil(NN/256)

// ---- histogram: cnt[col[e]]++, deg[col[e]] += w[e] ----
__global__ void hist_kernel(const int* __restrict__ col, const float* __restrict__ w,
                            int* __restrict__ cnt, float* __restrict__ deg) {
    int e = blockIdx.x * blockDim.x + threadIdx.x;
    if (e < EE) {
        int c = col[e];
        atomicAdd(&cnt[c], 1);
        atomicAdd(&deg[c], w[e]);
    }
}

// ---- dis[i] = rsqrt(deg[i] + 1)  (self-loop weight 1) ----
__global__ void dis_kernel(const float* __restrict__ deg, float* __restrict__ dis) {
    int i = blockIdx.x * blockDim.x + threadIdx.x;
    if (i < NN) dis[i] = rsqrtf(deg[i] + 1.0f);
}

// ---- scan step 1: per-256-chunk sums ----
__global__ __launch_bounds__(256) void partial_kernel(const int* __restrict__ cnt,
                                                      int* __restrict__ psum) {
    __shared__ int sd[256];
    int t = threadIdx.x;
    int i = blockIdx.x * 256 + t;
    sd[t] = (i < NN) ? cnt[i] : 0;
    __syncthreads();
    for (int off = 128; off; off >>= 1) {
        if (t < off) sd[t] += sd[t + off];
        __syncthreads();
    }
    if (t == 0) psum[blockIdx.x] = sd[0];
}

// ---- scan step 2: exclusive scan of the 391 partials (one block) ----
__global__ __launch_bounds__(512) void scanp_kernel(const int* __restrict__ psum,
                                                    int* __restrict__ poff) {
    __shared__ int sd[512];
    int t = threadIdx.x;
    int v = (t < NBLK) ? psum[t] : 0;
    sd[t] = v;
    __syncthreads();
    for (int off = 1; off < 512; off <<= 1) {
        int u = (t >= off) ? sd[t - off] : 0;
        __syncthreads();
        sd[t] += u;
        __syncthreads();
    }
    if (t < NBLK) poff[t] = sd[t] - v;   // exclusive
}

// ---- scan step 3: per-chunk exclusive scan + offset -> base, cursor ----
__global__ __launch_bounds__(256) void scanc_kernel(const int* __restrict__ cnt,
                                                    const int* __restrict__ poff,
                                                    int* __restrict__ base,
                                                    int* __restrict__ cursor) {
    __shared__ int sd[256];
    int t = threadIdx.x;
    int i = blockIdx.x * 256 + t;
    int c = (i < NN) ? cnt[i] : 0;
    sd[t] = c;
    __syncthreads();
    for (int off = 1; off < 256; off <<= 1) {
        int u = (t >= off) ? sd[t - off] : 0;
        __syncthreads();
        sd[t] += u;
        __syncthreads();
    }
    if (i < NN) {
        int excl = sd[t] - c + poff[blockIdx.x];
        base[i] = excl;
        cursor[i] = excl;
    }
}

// ---- fill CSR: slot = cursor[c]++; erow[slot]=row; enorm[slot]=norm ----
__global__ void fill_kernel(const int* __restrict__ row, const int* __restrict__ col,
                            const float* __restrict__ w, const float* __restrict__ dis,
                            int* __restrict__ cursor, int* __restrict__ erow,
                            float* __restrict__ enorm) {
    int e = blockIdx.x * blockDim.x + threadIdx.x;
    if (e >= EE) return;
    int c = col[e], r = row[e];
    int p = atomicAdd(&cursor[c], 1);
    erow[p] = r;
    enorm[p] = dis[r] * w[e] * dis[c];
}

// ---- GEMM1: xw[N,64] = x[N,256] @ W1[256,64]. 64-row tile, 4x4 micro-tile ----
__global__ __launch_bounds__(256) void gemm1_kernel(const float* __restrict__ x,
                                                    const float* __restrict__ W,
                                                    float* __restrict__ xw) {
    __shared__ float xs[64][65];
    __shared__ float Ws[64][72];
    const int tid = threadIdx.x;
    const int base = blockIdx.x * 64;
    const int ty = tid >> 4;
    const int tx = tid & 15;
    float acc[4][4] = {};

    for (int kb = 0; kb < FIN; kb += 64) {
        for (int v = tid; v < 1024; v += 256) {
            int r = v >> 4, q = v & 15;
            int gr = base + r;
            float4 xv = make_float4(0.f, 0.f, 0.f, 0.f);
            if (gr < NN) xv = *(const float4*)(x + (size_t)gr * FIN + kb + q * 4);
            xs[r][q * 4 + 0] = xv.x; xs[r][q * 4 + 1] = xv.y;
            xs[r][q * 4 + 2] = xv.z; xs[r][q * 4 + 3] = xv.w;
        }
        for (int v = tid; v < 1024; v += 256) {
            int k = v >> 4, q = v & 15;
            float4 wv = *(const float4*)(W + (size_t)(kb + k) * HID + q * 4);
            *(float4*)(&Ws[k][q * 4]) = wv;
        }
        __syncthreads();
#pragma unroll 8
        for (int k = 0; k < 64; k++) {
            float4 wv = *(const float4*)(&Ws[k][tx * 4]);
            float x0 = xs[ty * 4 + 0][k];
            float x1 = xs[ty * 4 + 1][k];
            float x2 = xs[ty * 4 + 2][k];
            float x3 = xs[ty * 4 + 3][k];
            acc[0][0] += x0 * wv.x; acc[0][1] += x0 * wv.y; acc[0][2] += x0 * wv.z; acc[0][3] += x0 * wv.w;
            acc[1][0] += x1 * wv.x; acc[1][1] += x1 * wv.y; acc[1][2] += x1 * wv.z; acc[1][3] += x1 * wv.w;
            acc[2][0] += x2 * wv.x; acc[2][1] += x2 * wv.y; acc[2][2] += x2 * wv.z; acc[2][3] += x2 * wv.w;
            acc[3][0] += x3 * wv.x; acc[3][1] += x3 * wv.y; acc[3][2] += x3 * wv.z; acc[3][3] += x3 * wv.w;
        }
        __syncthreads();
    }
#pragma unroll
    for (int i = 0; i < 4; i++) {
        int gr = base + ty * 4 + i;
        if (gr < NN)
            *(float4*)(xw + (size_t)gr * HID + tx * 4) =
                make_float4(acc[i][0], acc[i][1], acc[i][2], acc[i][3]);
    }
}

// ---- gather1: h[n,f] = relu(sum_in norm*xw[r,f] + dis^2*xw[n,f] + b1[f]) ----
__global__ __launch_bounds__(256) void gather1_kernel(const int* __restrict__ base,
                                                      const int* __restrict__ cursor,
                                                      const int* __restrict__ erow,
                                                      const float* __restrict__ enorm,
                                                      const float* __restrict__ xw,
                                                      const float* __restrict__ dis,
                                                      const float* __restrict__ b,
                                                      float* __restrict__ h) {
    int n = blockIdx.x * 4 + (threadIdx.x >> 6);
    if (n >= NN) return;
    int lane = threadIdx.x & 63;
    int s = base[n], t = cursor[n];
    float acc = 0.f;
    for (int p = s; p < t; ++p) {
        int r = erow[p];
        float nr = enorm[p];
        acc += nr * xw[(size_t)r * HID + lane];
    }
    float d = dis[n];
    float v = acc + d * d * xw[(size_t)n * HID + lane] + b[lane];
    h[(size_t)n * HID + lane] = fmaxf(v, 0.f);
}

// ---- GEMM2: hw2[N,40] = h[N,64] @ W2[64,40]. 64-row tile, 2x5 micro-tile ----
__global__ __launch_bounds__(256) void gemm2_kernel(const float* __restrict__ h,
                                                    const float* __restrict__ W,
                                                    float* __restrict__ hw) {
    __shared__ float hs[64][65];
    __shared__ float Ws[HID * NC];
    const int tid = threadIdx.x;
    const int base = blockIdx.x * 64;
    for (int v = tid; v < 1024; v += 256) {
        int r = v >> 4, q = v & 15;
        int gr = base + r;
        float4 hv = make_float4(0.f, 0.f, 0.f, 0.f);
        if (gr < NN) hv = *(const float4*)(h + (size_t)gr * HID + q * 4);
        hs[r][q * 4 + 0] = hv.x; hs[r][q * 4 + 1] = hv.y;
        hs[r][q * 4 + 2] = hv.z; hs[r][q * 4 + 3] = hv.w;
    }
    for (int v = tid; v < HID * NC; v += 256) Ws[v] = W[v];
    __syncthreads();
    const int tx = tid & 7;
    const int ty = tid >> 3;
    float acc[2][5] = {};
#pragma unroll 8
    for (int k = 0; k < HID; k++) {
        float h0 = hs[ty * 2 + 0][k];
        float h1 = hs[ty * 2 + 1][k];
        const float* wr = &Ws[k * NC + tx * 5];
        float w0 = wr[0], w1 = wr[1], w2 = wr[2], w3 = wr[3], w4 = wr[4];
        acc[0][0] += h0 * w0; acc[0][1] += h0 * w1; acc[0][2] += h0 * w2;
        acc[0][3] += h0 * w3; acc[0][4] += h0 * w4;
        acc[1][0] += h1 * w0; acc[1][1] += h1 * w1; acc[1][2] += h1 * w2;
        acc[1][3] += h1 * w3; acc[1][4] += h1 * w4;
    }
#pragma unroll
    for (int i = 0; i < 2; i++) {
        int gr = base + ty * 2 + i;
        if (gr < NN) {
#pragma unroll
            for (int c = 0; c < 5; c++) hw[(size_t)gr * NC + tx * 5 + c] = acc[i][c];
        }
    }
}

// ---- gather2 + final: out = agg + dis^2*hw + b2 ; log_softmax fused ----
__global__ __launch_bounds__(256) void gather2_kernel(const int* __restrict__ base,
                                                      const int* __restrict__ cursor,
                                                      const int* __restrict__ erow,
                                                      const float* __restrict__ enorm,
                                                      const float* __restrict__ hw,
                                                      const float* __restrict__ dis,
                                                      const float* __restrict__ b,
                                                      float* __restrict__ out) {
    int n = blockIdx.x * 4 + (threadIdx.x >> 6);
    if (n >= NN) return;
    int lane = threadIdx.x & 63;
    bool act = lane < NC;
    int s = base[n], t = cursor[n];
    float acc = 0.f;
    for (int p = s; p < t; ++p) {
        int r = erow[p];
        float nr = enorm[p];
        float hv = act ? hw[(size_t)r * NC + lane] : 0.f;
        acc += nr * hv;
    }
    float val = 0.f, v = -INFINITY;
    if (act) {
        float d = dis[n];
        val = acc + d * d * hw[(size_t)n * NC + lane] + b[lane];
        v = val;
    }
    float m = v;
#pragma unroll
    for (int off = 32; off; off >>= 1) m = fmaxf(m, __shfl_xor(m, off));
    float e = act ? expf(val - m) : 0.f;
    float sum = e;
#pragma unroll
    for (int off = 32; off; off >>= 1) sum += __shfl_xor(sum, off);
    float lse = m + logf(sum);
    if (act) {
        size_t idx = (size_t)n * NC + lane;
        out[idx] = val;
        out[(size_t)NN * NC + idx] = val - lse;
    }
}

extern "C" void kernel_launch(void* const* d_in, const int* in_sizes, int n_in,
                              void* d_out, int out_size, void* d_ws, size_t ws_size,
                              hipStream_t stream) {
    const float* x    = (const float*)d_in[0];
    const int*   eidx = (const int*)d_in[1];
    const float* ew   = (const float*)d_in[2];
    const float* W1   = (const float*)d_in[3];
    const float* b1   = (const float*)d_in[4];
    const float* W2   = (const float*)d_in[5];
    const float* b2   = (const float*)d_in[6];
    float* out = (float*)d_out;

    const int* row = eidx;
    const int* col = eidx + EE;

    char* ws = (char*)d_ws;
    float* deg    = (float*)ws;                 ws += NN * 4;
    float* dis    = (float*)ws;                 ws += NN * 4;
    int*   cnt    = (int*)ws;                   ws += NN * 4;
    int*   psum   = (int*)ws;                   ws += 512 * 4;
    int*   poff   = (int*)ws;                   ws += 512 * 4;
    int*   basev  = (int*)ws;                   ws += NN * 4;
    int*   cursor = (int*)ws;                   ws += NN * 4;
    int*   erow   = (int*)ws;                   ws += (size_t)EE * 4;
    float* enorm  = (float*)ws;                 ws += (size_t)EE * 4;
    float* xw     = (float*)ws;                 ws += (size_t)NN * HID * 4;
    float* h      = (float*)ws;                 ws += (size_t)NN * HID * 4;
    float* hw2    = (float*)ws;                 ws += (size_t)NN * NC * 4;

    hipMemsetAsync(deg, 0, NN * 4, stream);
    hipMemsetAsync(cnt, 0, NN * 4, stream);

    hist_kernel<<<(EE + 255) / 256, 256, 0, stream>>>(col, ew, cnt, deg);
    dis_kernel<<<(NN + 255) / 256, 256, 0, stream>>>(deg, dis);
    partial_kernel<<<NBLK, 256, 0, stream>>>(cnt, psum);
    scanp_kernel<<<1, 512, 0, stream>>>(psum, poff);
    scanc_kernel<<<NBLK, 256, 0, stream>>>(cnt, poff, basev, cursor);
    fill_kernel<<<(EE + 255) / 256, 256, 0, stream>>>(row, col, ew, dis, cursor, erow, enorm);
    gemm1_kernel<<<(NN + 63) / 64, 256, 0, stream>>>(x, W1, xw);
    gather1_kernel<<<(NN + 3) / 4, 256, 0, stream>>>(basev, cursor, erow, enorm, xw, dis, b1, h);
    gemm2_kernel<<<(NN + 63) / 64, 256, 0, stream>>>(h, W2, hw2);
    gather2_kernel<<<(NN + 3) / 4, 256, 0, stream>>>(basev, cursor, erow, enorm, hw2, dis, b2, out);
}

// Round 4
// 647.162 us; speedup vs baseline: 2.1283x; 1.2432x over previous
//
#include <hip/hip_runtime.h>
#include <hip/hip_bf16.h>
#include <math.h>

#define NN 100000
#define EE 1600000
#define FIN 256
#define HID 64
#define NC 40
#define NBLK 391   // ceil(NN/256)

// ---- histogram: cnt[col[e]]++, deg[col[e]] += w[e] ----
__global__ void hist_kernel(const int* __restrict__ col, const float* __restrict__ w,
                            int* __restrict__ cnt, float* __restrict__ deg) {
    int e = blockIdx.x * blockDim.x + threadIdx.x;
    if (e < EE) {
        int c = col[e];
        atomicAdd(&cnt[c], 1);
        atomicAdd(&deg[c], w[e]);
    }
}

// ---- dis[i] = rsqrt(deg[i] + 1) ----
__global__ void dis_kernel(const float* __restrict__ deg, float* __restrict__ dis) {
    int i = blockIdx.x * blockDim.x + threadIdx.x;
    if (i < NN) dis[i] = rsqrtf(deg[i] + 1.0f);
}

// ---- scan step 1: per-256-chunk sums ----
__global__ __launch_bounds__(256) void partial_kernel(const int* __restrict__ cnt,
                                                      int* __restrict__ psum) {
    __shared__ int sd[256];
    int t = threadIdx.x;
    int i = blockIdx.x * 256 + t;
    sd[t] = (i < NN) ? cnt[i] : 0;
    __syncthreads();
    for (int off = 128; off; off >>= 1) {
        if (t < off) sd[t] += sd[t + off];
        __syncthreads();
    }
    if (t == 0) psum[blockIdx.x] = sd[0];
}

// ---- scan step 2: exclusive scan of partials (one block) ----
__global__ __launch_bounds__(512) void scanp_kernel(const int* __restrict__ psum,
                                                    int* __restrict__ poff) {
    __shared__ int sd[512];
    int t = threadIdx.x;
    int v = (t < NBLK) ? psum[t] : 0;
    sd[t] = v;
    __syncthreads();
    for (int off = 1; off < 512; off <<= 1) {
        int u = (t >= off) ? sd[t - off] : 0;
        __syncthreads();
        sd[t] += u;
        __syncthreads();
    }
    if (t < NBLK) poff[t] = sd[t] - v;   // exclusive
}

// ---- scan step 3: per-chunk exclusive scan + offset -> base, cursor ----
__global__ __launch_bounds__(256) void scanc_kernel(const int* __restrict__ cnt,
                                                    const int* __restrict__ poff,
                                                    int* __restrict__ base,
                                                    int* __restrict__ cursor) {
    __shared__ int sd[256];
    int t = threadIdx.x;
    int i = blockIdx.x * 256 + t;
    int c = (i < NN) ? cnt[i] : 0;
    sd[t] = c;
    __syncthreads();
    for (int off = 1; off < 256; off <<= 1) {
        int u = (t >= off) ? sd[t - off] : 0;
        __syncthreads();
        sd[t] += u;
        __syncthreads();
    }
    if (i < NN) {
        int excl = sd[t] - c + poff[blockIdx.x];
        base[i] = excl;
        cursor[i] = excl;
    }
}

// ---- fill CSR: eme[slot] = {row, norm_bits} ----
__global__ void fill_kernel(const int* __restrict__ row, const int* __restrict__ col,
                            const float* __restrict__ w, const float* __restrict__ dis,
                            int* __restrict__ cursor, int2* __restrict__ eme) {
    int e = blockIdx.x * blockDim.x + threadIdx.x;
    if (e >= EE) return;
    int c = col[e], r = row[e];
    int p = atomicAdd(&cursor[c], 1);
    eme[p] = make_int2(r, __float_as_int(dis[r] * w[e] * dis[c]));
}

// ---- GEMM1: xw[N,64](bf16) = x[N,256] @ W1[256,64] ----
__global__ __launch_bounds__(256) void gemm1_kernel(const float* __restrict__ x,
                                                    const float* __restrict__ W,
                                                    __hip_bfloat16* __restrict__ xw) {
    __shared__ float xs[64][65];
    __shared__ float Ws[64][72];
    const int tid = threadIdx.x;
    const int base = blockIdx.x * 64;
    const int ty = tid >> 4;
    const int tx = tid & 15;
    float acc[4][4] = {};

    for (int kb = 0; kb < FIN; kb += 64) {
        for (int v = tid; v < 1024; v += 256) {
            int r = v >> 4, q = v & 15;
            int gr = base + r;
            float4 xv = make_float4(0.f, 0.f, 0.f, 0.f);
            if (gr < NN) xv = *(const float4*)(x + (size_t)gr * FIN + kb + q * 4);
            xs[r][q * 4 + 0] = xv.x; xs[r][q * 4 + 1] = xv.y;
            xs[r][q * 4 + 2] = xv.z; xs[r][q * 4 + 3] = xv.w;
        }
        for (int v = tid; v < 1024; v += 256) {
            int k = v >> 4, q = v & 15;
            float4 wv = *(const float4*)(W + (size_t)(kb + k) * HID + q * 4);
            *(float4*)(&Ws[k][q * 4]) = wv;
        }
        __syncthreads();
#pragma unroll 8
        for (int k = 0; k < 64; k++) {
            float4 wv = *(const float4*)(&Ws[k][tx * 4]);
            float x0 = xs[ty * 4 + 0][k];
            float x1 = xs[ty * 4 + 1][k];
            float x2 = xs[ty * 4 + 2][k];
            float x3 = xs[ty * 4 + 3][k];
            acc[0][0] += x0 * wv.x; acc[0][1] += x0 * wv.y; acc[0][2] += x0 * wv.z; acc[0][3] += x0 * wv.w;
            acc[1][0] += x1 * wv.x; acc[1][1] += x1 * wv.y; acc[1][2] += x1 * wv.z; acc[1][3] += x1 * wv.w;
            acc[2][0] += x2 * wv.x; acc[2][1] += x2 * wv.y; acc[2][2] += x2 * wv.z; acc[2][3] += x2 * wv.w;
            acc[3][0] += x3 * wv.x; acc[3][1] += x3 * wv.y; acc[3][2] += x3 * wv.z; acc[3][3] += x3 * wv.w;
        }
        __syncthreads();
    }
#pragma unroll
    for (int i = 0; i < 4; i++) {
        int gr = base + ty * 4 + i;
        if (gr < NN) {
            union { __hip_bfloat16 h[4]; uint2 u; } pk;
            pk.h[0] = __float2bfloat16(acc[i][0]);
            pk.h[1] = __float2bfloat16(acc[i][1]);
            pk.h[2] = __float2bfloat16(acc[i][2]);
            pk.h[3] = __float2bfloat16(acc[i][3]);
            *(uint2*)(xw + (size_t)gr * HID + tx * 4) = pk.u;
        }
    }
}

// ---- gather1: h[n,f] = relu(sum norm*xw[r,f] + dis^2*xw[n,f] + b1[f]) ----
__global__ __launch_bounds__(256) void gather1_kernel(const int* __restrict__ base,
                                                      const int* __restrict__ cursor,
                                                      const int2* __restrict__ eme,
                                                      const __hip_bfloat16* __restrict__ xw,
                                                      const float* __restrict__ dis,
                                                      const float* __restrict__ b,
                                                      float* __restrict__ h) {
    int n = blockIdx.x * 4 + (threadIdx.x >> 6);
    if (n >= NN) return;
    int lane = threadIdx.x & 63;
    int s = base[n], t = cursor[n];
    float acc = 0.f;
    int p = s;
    for (; p + 4 <= t; p += 4) {
        int2 e0 = eme[p], e1 = eme[p + 1], e2 = eme[p + 2], e3 = eme[p + 3];
        float v0 = __bfloat162float(xw[(size_t)e0.x * HID + lane]);
        float v1 = __bfloat162float(xw[(size_t)e1.x * HID + lane]);
        float v2 = __bfloat162float(xw[(size_t)e2.x * HID + lane]);
        float v3 = __bfloat162float(xw[(size_t)e3.x * HID + lane]);
        acc += __int_as_float(e0.y) * v0 + __int_as_float(e1.y) * v1
             + __int_as_float(e2.y) * v2 + __int_as_float(e3.y) * v3;
    }
    for (; p < t; ++p) {
        int2 e = eme[p];
        acc += __int_as_float(e.y) * __bfloat162float(xw[(size_t)e.x * HID + lane]);
    }
    float d = dis[n];
    float v = acc + d * d * __bfloat162float(xw[(size_t)n * HID + lane]) + b[lane];
    h[(size_t)n * HID + lane] = fmaxf(v, 0.f);
}

// ---- GEMM2: hw2[N,40](bf16) = h[N,64] @ W2[64,40] ----
__global__ __launch_bounds__(256) void gemm2_kernel(const float* __restrict__ h,
                                                    const float* __restrict__ W,
                                                    __hip_bfloat16* __restrict__ hw) {
    __shared__ float hs[64][65];
    __shared__ float Ws[HID * NC];
    const int tid = threadIdx.x;
    const int base = blockIdx.x * 64;
    for (int v = tid; v < 1024; v += 256) {
        int r = v >> 4, q = v & 15;
        int gr = base + r;
        float4 hv = make_float4(0.f, 0.f, 0.f, 0.f);
        if (gr < NN) hv = *(const float4*)(h + (size_t)gr * HID + q * 4);
        hs[r][q * 4 + 0] = hv.x; hs[r][q * 4 + 1] = hv.y;
        hs[r][q * 4 + 2] = hv.z; hs[r][q * 4 + 3] = hv.w;
    }
    for (int v = tid; v < HID * NC; v += 256) Ws[v] = W[v];
    __syncthreads();
    const int tx = tid & 7;
    const int ty = tid >> 3;
    float acc[2][5] = {};
#pragma unroll 8
    for (int k = 0; k < HID; k++) {
        float h0 = hs[ty * 2 + 0][k];
        float h1 = hs[ty * 2 + 1][k];
        const float* wr = &Ws[k * NC + tx * 5];
        float w0 = wr[0], w1 = wr[1], w2 = wr[2], w3 = wr[3], w4 = wr[4];
        acc[0][0] += h0 * w0; acc[0][1] += h0 * w1; acc[0][2] += h0 * w2;
        acc[0][3] += h0 * w3; acc[0][4] += h0 * w4;
        acc[1][0] += h1 * w0; acc[1][1] += h1 * w1; acc[1][2] += h1 * w2;
        acc[1][3] += h1 * w3; acc[1][4] += h1 * w4;
    }
#pragma unroll
    for (int i = 0; i < 2; i++) {
        int gr = base + ty * 2 + i;
        if (gr < NN) {
#pragma unroll
            for (int c = 0; c < 5; c++)
                hw[(size_t)gr * NC + tx * 5 + c] = __float2bfloat16(acc[i][c]);
        }
    }
}

// ---- gather2 + final: out = agg + dis^2*hw + b2 ; log_softmax fused ----
__global__ __launch_bounds__(256) void gather2_kernel(const int* __restrict__ base,
                                                      const int* __restrict__ cursor,
                                                      const int2* __restrict__ eme,
                                                      const __hip_bfloat16* __restrict__ hw,
                                                      const float* __restrict__ dis,
                                                      const float* __restrict__ b,
                                                      float* __restrict__ out) {
    int n = blockIdx.x * 4 + (threadIdx.x >> 6);
    if (n >= NN) return;
    int lane = threadIdx.x & 63;
    bool act = lane < NC;
    int s = base[n], t = cursor[n];
    float acc = 0.f;
    int p = s;
    for (; p + 4 <= t; p += 4) {
        int2 e0 = eme[p], e1 = eme[p + 1], e2 = eme[p + 2], e3 = eme[p + 3];
        float v0 = act ? __bfloat162float(hw[(size_t)e0.x * NC + lane]) : 0.f;
        float v1 = act ? __bfloat162float(hw[(size_t)e1.x * NC + lane]) : 0.f;
        float v2 = act ? __bfloat162float(hw[(size_t)e2.x * NC + lane]) : 0.f;
        float v3 = act ? __bfloat162float(hw[(size_t)e3.x * NC + lane]) : 0.f;
        acc += __int_as_float(e0.y) * v0 + __int_as_float(e1.y) * v1
             + __int_as_float(e2.y) * v2 + __int_as_float(e3.y) * v3;
    }
    for (; p < t; ++p) {
        int2 e = eme[p];
        float hv = act ? __bfloat162float(hw[(size_t)e.x * NC + lane]) : 0.f;
        acc += __int_as_float(e.y) * hv;
    }
    float val = 0.f, v = -INFINITY;
    if (act) {
        float d = dis[n];
        val = acc + d * d * __bfloat162float(hw[(size_t)n * NC + lane]) + b[lane];
        v = val;
    }
    float m = v;
#pragma unroll
    for (int off = 32; off; off >>= 1) m = fmaxf(m, __shfl_xor(m, off));
    float e = act ? expf(val - m) : 0.f;
    float sum = e;
#pragma unroll
    for (int off = 32; off; off >>= 1) sum += __shfl_xor(sum, off);
    float lse = m + logf(sum);
    if (act) {
        size_t idx = (size_t)n * NC + lane;
        out[idx] = val;
        out[(size_t)NN * NC + idx] = val - lse;
    }
}

extern "C" void kernel_launch(void* const* d_in, const int* in_sizes, int n_in,
                              void* d_out, int out_size, void* d_ws, size_t ws_size,
                              hipStream_t stream) {
    const float* x    = (const float*)d_in[0];
    const int*   eidx = (const int*)d_in[1];
    const float* ew   = (const float*)d_in[2];
    const float* W1   = (const float*)d_in[3];
    const float* b1   = (const float*)d_in[4];
    const float* W2   = (const float*)d_in[5];
    const float* b2   = (const float*)d_in[6];
    float* out = (float*)d_out;

    const int* row = eidx;
    const int* col = eidx + EE;

    char* ws = (char*)d_ws;
    float* deg    = (float*)ws;                 ws += NN * 4;
    float* dis    = (float*)ws;                 ws += NN * 4;
    int*   cnt    = (int*)ws;                   ws += NN * 4;
    int*   psum   = (int*)ws;                   ws += 512 * 4;
    int*   poff   = (int*)ws;                   ws += 512 * 4;
    int*   basev  = (int*)ws;                   ws += NN * 4;
    int*   cursor = (int*)ws;                   ws += NN * 4;
    int2*  eme    = (int2*)ws;                  ws += (size_t)EE * 8;
    __hip_bfloat16* xw = (__hip_bfloat16*)ws;   ws += (size_t)NN * HID * 2;
    float* h      = (float*)ws;                 ws += (size_t)NN * HID * 4;
    __hip_bfloat16* hw2 = (__hip_bfloat16*)ws;  ws += (size_t)NN * NC * 2;

    hipMemsetAsync(deg, 0, NN * 4, stream);
    hipMemsetAsync(cnt, 0, NN * 4, stream);

    hist_kernel<<<(EE + 255) / 256, 256, 0, stream>>>(col, ew, cnt, deg);
    dis_kernel<<<(NN + 255) / 256, 256, 0, stream>>>(deg, dis);
    partial_kernel<<<NBLK, 256, 0, stream>>>(cnt, psum);
    scanp_kernel<<<1, 512, 0, stream>>>(psum, poff);
    scanc_kernel<<<NBLK, 256, 0, stream>>>(cnt, poff, basev, cursor);
    fill_kernel<<<(EE + 255) / 256, 256, 0, stream>>>(row, col, ew, dis, cursor, eme);
    gemm1_kernel<<<(NN + 63) / 64, 256, 0, stream>>>(x, W1, xw);
    gather1_kernel<<<(NN + 3) / 4, 256, 0, stream>>>(basev, cursor, eme, xw, dis, b1, h);
    gemm2_kernel<<<(NN + 63) / 64, 256, 0, stream>>>(h, W2, hw2);
    gather2_kernel<<<(NN + 3) / 4, 256, 0, stream>>>(basev, cursor, eme, hw2, dis, b2, out);
}

// Round 5
// 574.469 us; speedup vs baseline: 2.3976x; 1.1265x over previous
//
#include <hip/hip_runtime.h>
#include <hip/hip_bf16.h>
#include <math.h>

#define NN 100000
#define EE 1600000
#define FIN 256
#define HID 64
#define NC 40
#define NBLK 391   // ceil(NN/256)

// ---- histogram: one packed u64 atomic per edge.
//      pk[c] += (1<<40) | round(w * 2^20)   (count:24 bits | fixedpoint-sum:40 bits)
__global__ void hist_kernel(const int* __restrict__ col, const float* __restrict__ w,
                            unsigned long long* __restrict__ pk) {
    int e = blockIdx.x * blockDim.x + threadIdx.x;
    if (e < EE) {
        int c = col[e];
        unsigned long long v = (1ULL << 40) |
            (unsigned long long)__float2uint_rn(w[e] * 1048576.0f);
        atomicAdd(&pk[c], v);
    }
}

// ---- unpack: cnt[i] = count, dis[i] = rsqrt(deg + 1) ----
__global__ void dis_kernel(const unsigned long long* __restrict__ pk,
                           int* __restrict__ cnt, float* __restrict__ dis) {
    int i = blockIdx.x * blockDim.x + threadIdx.x;
    if (i < NN) {
        unsigned long long v = pk[i];
        cnt[i] = (int)(v >> 40);
        float deg = (float)(v & ((1ULL << 40) - 1)) * (1.0f / 1048576.0f);
        dis[i] = rsqrtf(deg + 1.0f);
    }
}

// ---- scan step 1: per-256-chunk sums ----
__global__ __launch_bounds__(256) void partial_kernel(const int* __restrict__ cnt,
                                                      int* __restrict__ psum) {
    __shared__ int sd[256];
    int t = threadIdx.x;
    int i = blockIdx.x * 256 + t;
    sd[t] = (i < NN) ? cnt[i] : 0;
    __syncthreads();
    for (int off = 128; off; off >>= 1) {
        if (t < off) sd[t] += sd[t + off];
        __syncthreads();
    }
    if (t == 0) psum[blockIdx.x] = sd[0];
}

// ---- scan step 2: exclusive scan of partials (one block) ----
__global__ __launch_bounds__(512) void scanp_kernel(const int* __restrict__ psum,
                                                    int* __restrict__ poff) {
    __shared__ int sd[512];
    int t = threadIdx.x;
    int v = (t < NBLK) ? psum[t] : 0;
    sd[t] = v;
    __syncthreads();
    for (int off = 1; off < 512; off <<= 1) {
        int u = (t >= off) ? sd[t - off] : 0;
        __syncthreads();
        sd[t] += u;
        __syncthreads();
    }
    if (t < NBLK) poff[t] = sd[t] - v;   // exclusive
}

// ---- scan step 3: per-chunk exclusive scan + offset -> base, cursor ----
__global__ __launch_bounds__(256) void scanc_kernel(const int* __restrict__ cnt,
                                                    const int* __restrict__ poff,
                                                    int* __restrict__ base,
                                                    int* __restrict__ cursor) {
    __shared__ int sd[256];
    int t = threadIdx.x;
    int i = blockIdx.x * 256 + t;
    int c = (i < NN) ? cnt[i] : 0;
    sd[t] = c;
    __syncthreads();
    for (int off = 1; off < 256; off <<= 1) {
        int u = (t >= off) ? sd[t - off] : 0;
        __syncthreads();
        sd[t] += u;
        __syncthreads();
    }
    if (i < NN) {
        int excl = sd[t] - c + poff[blockIdx.x];
        base[i] = excl;
        cursor[i] = excl;
    }
}

// ---- fill CSR: eme[slot] = {row, norm_bits} ----
__global__ void fill_kernel(const int* __restrict__ row, const int* __restrict__ col,
                            const float* __restrict__ w, const float* __restrict__ dis,
                            int* __restrict__ cursor, int2* __restrict__ eme) {
    int e = blockIdx.x * blockDim.x + threadIdx.x;
    if (e >= EE) return;
    int c = col[e], r = row[e];
    int p = atomicAdd(&cursor[c], 1);
    eme[p] = make_int2(r, __float_as_int(dis[r] * w[e] * dis[c]));
}

// ---- GEMM1: xw[N,64](bf16) = x[N,256] @ W1[256,64] ----
__global__ __launch_bounds__(256) void gemm1_kernel(const float* __restrict__ x,
                                                    const float* __restrict__ W,
                                                    __hip_bfloat16* __restrict__ xw) {
    __shared__ float xs[64][65];
    __shared__ float Ws[64][72];
    const int tid = threadIdx.x;
    const int base = blockIdx.x * 64;
    const int ty = tid >> 4;
    const int tx = tid & 15;
    float acc[4][4] = {};

    for (int kb = 0; kb < FIN; kb += 64) {
        for (int v = tid; v < 1024; v += 256) {
            int r = v >> 4, q = v & 15;
            int gr = base + r;
            float4 xv = make_float4(0.f, 0.f, 0.f, 0.f);
            if (gr < NN) xv = *(const float4*)(x + (size_t)gr * FIN + kb + q * 4);
            xs[r][q * 4 + 0] = xv.x; xs[r][q * 4 + 1] = xv.y;
            xs[r][q * 4 + 2] = xv.z; xs[r][q * 4 + 3] = xv.w;
        }
        for (int v = tid; v < 1024; v += 256) {
            int k = v >> 4, q = v & 15;
            float4 wv = *(const float4*)(W + (size_t)(kb + k) * HID + q * 4);
            *(float4*)(&Ws[k][q * 4]) = wv;
        }
        __syncthreads();
#pragma unroll 8
        for (int k = 0; k < 64; k++) {
            float4 wv = *(const float4*)(&Ws[k][tx * 4]);
            float x0 = xs[ty * 4 + 0][k];
            float x1 = xs[ty * 4 + 1][k];
            float x2 = xs[ty * 4 + 2][k];
            float x3 = xs[ty * 4 + 3][k];
            acc[0][0] += x0 * wv.x; acc[0][1] += x0 * wv.y; acc[0][2] += x0 * wv.z; acc[0][3] += x0 * wv.w;
            acc[1][0] += x1 * wv.x; acc[1][1] += x1 * wv.y; acc[1][2] += x1 * wv.z; acc[1][3] += x1 * wv.w;
            acc[2][0] += x2 * wv.x; acc[2][1] += x2 * wv.y; acc[2][2] += x2 * wv.z; acc[2][3] += x2 * wv.w;
            acc[3][0] += x3 * wv.x; acc[3][1] += x3 * wv.y; acc[3][2] += x3 * wv.z; acc[3][3] += x3 * wv.w;
        }
        __syncthreads();
    }
#pragma unroll
    for (int i = 0; i < 4; i++) {
        int gr = base + ty * 4 + i;
        if (gr < NN) {
            union { __hip_bfloat16 h[4]; uint2 u; } pkd;
            pkd.h[0] = __float2bfloat16(acc[i][0]);
            pkd.h[1] = __float2bfloat16(acc[i][1]);
            pkd.h[2] = __float2bfloat16(acc[i][2]);
            pkd.h[3] = __float2bfloat16(acc[i][3]);
            *(uint2*)(xw + (size_t)gr * HID + tx * 4) = pkd.u;
        }
    }
}

// ---- gather1: h[n,f] = relu(sum norm*xw[r,f] + dis^2*xw[n,f] + b1[f]) ----
__global__ __launch_bounds__(256) void gather1_kernel(const int* __restrict__ base,
                                                      const int* __restrict__ cursor,
                                                      const int2* __restrict__ eme,
                                                      const __hip_bfloat16* __restrict__ xw,
                                                      const float* __restrict__ dis,
                                                      const float* __restrict__ b,
                                                      float* __restrict__ h) {
    int n = blockIdx.x * 4 + (threadIdx.x >> 6);
    if (n >= NN) return;
    int lane = threadIdx.x & 63;
    int s = base[n], t = cursor[n];
    float acc = 0.f;
    int p = s;
    for (; p + 4 <= t; p += 4) {
        int2 e0 = eme[p], e1 = eme[p + 1], e2 = eme[p + 2], e3 = eme[p + 3];
        float v0 = __bfloat162float(xw[(size_t)e0.x * HID + lane]);
        float v1 = __bfloat162float(xw[(size_t)e1.x * HID + lane]);
        float v2 = __bfloat162float(xw[(size_t)e2.x * HID + lane]);
        float v3 = __bfloat162float(xw[(size_t)e3.x * HID + lane]);
        acc += __int_as_float(e0.y) * v0 + __int_as_float(e1.y) * v1
             + __int_as_float(e2.y) * v2 + __int_as_float(e3.y) * v3;
    }
    for (; p < t; ++p) {
        int2 e = eme[p];
        acc += __int_as_float(e.y) * __bfloat162float(xw[(size_t)e.x * HID + lane]);
    }
    float d = dis[n];
    float v = acc + d * d * __bfloat162float(xw[(size_t)n * HID + lane]) + b[lane];
    h[(size_t)n * HID + lane] = fmaxf(v, 0.f);
}

// ---- GEMM2: hw2[N,40](bf16) = h[N,64] @ W2[64,40] ----
__global__ __launch_bounds__(256) void gemm2_kernel(const float* __restrict__ h,
                                                    const float* __restrict__ W,
                                                    __hip_bfloat16* __restrict__ hw) {
    __shared__ float hs[64][65];
    __shared__ float Ws[HID * NC];
    const int tid = threadIdx.x;
    const int base = blockIdx.x * 64;
    for (int v = tid; v < 1024; v += 256) {
        int r = v >> 4, q = v & 15;
        int gr = base + r;
        float4 hv = make_float4(0.f, 0.f, 0.f, 0.f);
        if (gr < NN) hv = *(const float4*)(h + (size_t)gr * HID + q * 4);
        hs[r][q * 4 + 0] = hv.x; hs[r][q * 4 + 1] = hv.y;
        hs[r][q * 4 + 2] = hv.z; hs[r][q * 4 + 3] = hv.w;
    }
    for (int v = tid; v < HID * NC; v += 256) Ws[v] = W[v];
    __syncthreads();
    const int tx = tid & 7;
    const int ty = tid >> 3;
    float acc[2][5] = {};
#pragma unroll 8
    for (int k = 0; k < HID; k++) {
        float h0 = hs[ty * 2 + 0][k];
        float h1 = hs[ty * 2 + 1][k];
        const float* wr = &Ws[k * NC + tx * 5];
        float w0 = wr[0], w1 = wr[1], w2 = wr[2], w3 = wr[3], w4 = wr[4];
        acc[0][0] += h0 * w0; acc[0][1] += h0 * w1; acc[0][2] += h0 * w2;
        acc[0][3] += h0 * w3; acc[0][4] += h0 * w4;
        acc[1][0] += h1 * w0; acc[1][1] += h1 * w1; acc[1][2] += h1 * w2;
        acc[1][3] += h1 * w3; acc[1][4] += h1 * w4;
    }
#pragma unroll
    for (int i = 0; i < 2; i++) {
        int gr = base + ty * 2 + i;
        if (gr < NN) {
#pragma unroll
            for (int c = 0; c < 5; c++)
                hw[(size_t)gr * NC + tx * 5 + c] = __float2bfloat16(acc[i][c]);
        }
    }
}

// ---- gather2 + final: out = agg + dis^2*hw + b2 ; log_softmax fused ----
__global__ __launch_bounds__(256) void gather2_kernel(const int* __restrict__ base,
                                                      const int* __restrict__ cursor,
                                                      const int2* __restrict__ eme,
                                                      const __hip_bfloat16* __restrict__ hw,
                                                      const float* __restrict__ dis,
                                                      const float* __restrict__ b,
                                                      float* __restrict__ out) {
    int n = blockIdx.x * 4 + (threadIdx.x >> 6);
    if (n >= NN) return;
    int lane = threadIdx.x & 63;
    bool act = lane < NC;
    int s = base[n], t = cursor[n];
    float acc = 0.f;
    int p = s;
    for (; p + 4 <= t; p += 4) {
        int2 e0 = eme[p], e1 = eme[p + 1], e2 = eme[p + 2], e3 = eme[p + 3];
        float v0 = act ? __bfloat162float(hw[(size_t)e0.x * NC + lane]) : 0.f;
        float v1 = act ? __bfloat162float(hw[(size_t)e1.x * NC + lane]) : 0.f;
        float v2 = act ? __bfloat162float(hw[(size_t)e2.x * NC + lane]) : 0.f;
        float v3 = act ? __bfloat162float(hw[(size_t)e3.x * NC + lane]) : 0.f;
        acc += __int_as_float(e0.y) * v0 + __int_as_float(e1.y) * v1
             + __int_as_float(e2.y) * v2 + __int_as_float(e3.y) * v3;
    }
    for (; p < t; ++p) {
        int2 e = eme[p];
        float hv = act ? __bfloat162float(hw[(size_t)e.x * NC + lane]) : 0.f;
        acc += __int_as_float(e.y) * hv;
    }
    float val = 0.f, v = -INFINITY;
    if (act) {
        float d = dis[n];
        val = acc + d * d * __bfloat162float(hw[(size_t)n * NC + lane]) + b[lane];
        v = val;
    }
    float m = v;
#pragma unroll
    for (int off = 32; off; off >>= 1) m = fmaxf(m, __shfl_xor(m, off));
    float e = act ? expf(val - m) : 0.f;
    float sum = e;
#pragma unroll
    for (int off = 32; off; off >>= 1) sum += __shfl_xor(sum, off);
    float lse = m + logf(sum);
    if (act) {
        size_t idx = (size_t)n * NC + lane;
        out[idx] = val;
        out[(size_t)NN * NC + idx] = val - lse;
    }
}

extern "C" void kernel_launch(void* const* d_in, const int* in_sizes, int n_in,
                              void* d_out, int out_size, void* d_ws, size_t ws_size,
                              hipStream_t stream) {
    const float* x    = (const float*)d_in[0];
    const int*   eidx = (const int*)d_in[1];
    const float* ew   = (const float*)d_in[2];
    const float* W1   = (const float*)d_in[3];
    const float* b1   = (const float*)d_in[4];
    const float* W2   = (const float*)d_in[5];
    const float* b2   = (const float*)d_in[6];
    float* out = (float*)d_out;

    const int* row = eidx;
    const int* col = eidx + EE;

    char* ws = (char*)d_ws;
    unsigned long long* pk = (unsigned long long*)ws; ws += NN * 8;
    float* dis    = (float*)ws;                 ws += NN * 4;
    int*   cnt    = (int*)ws;                   ws += NN * 4;
    int*   psum   = (int*)ws;                   ws += 512 * 4;
    int*   poff   = (int*)ws;                   ws += 512 * 4;
    int*   basev  = (int*)ws;                   ws += NN * 4;
    int*   cursor = (int*)ws;                   ws += NN * 4;
    int2*  eme    = (int2*)ws;                  ws += (size_t)EE * 8;
    __hip_bfloat16* xw = (__hip_bfloat16*)ws;   ws += (size_t)NN * HID * 2;
    float* h      = (float*)ws;                 ws += (size_t)NN * HID * 4;
    __hip_bfloat16* hw2 = (__hip_bfloat16*)ws;  ws += (size_t)NN * NC * 2;

    hipMemsetAsync(pk, 0, NN * 8, stream);

    hist_kernel<<<(EE + 255) / 256, 256, 0, stream>>>(col, ew, pk);
    dis_kernel<<<(NN + 255) / 256, 256, 0, stream>>>(pk, cnt, dis);
    partial_kernel<<<NBLK, 256, 0, stream>>>(cnt, psum);
    scanp_kernel<<<1, 512, 0, stream>>>(psum, poff);
    scanc_kernel<<<NBLK, 256, 0, stream>>>(cnt, poff, basev, cursor);
    fill_kernel<<<(EE + 255) / 256, 256, 0, stream>>>(row, col, ew, dis, cursor, eme);
    gemm1_kernel<<<(NN + 63) / 64, 256, 0, stream>>>(x, W1, xw);
    gather1_kernel<<<(NN + 3) / 4, 256, 0, stream>>>(basev, cursor, eme, xw, dis, b1, h);
    gemm2_kernel<<<(NN + 63) / 64, 256, 0, stream>>>(h, W2, hw2);
    gather2_kernel<<<(NN + 3) / 4, 256, 0, stream>>>(basev, cursor, eme, hw2, dis, b2, out);
}

// Round 6
// 460.021 us; speedup vs baseline: 2.9940x; 1.2488x over previous
//
#include <hip/hip_runtime.h>
#include <hip/hip_bf16.h>
#include <math.h>

#define NN 100000
#define EE 1600000
#define FIN 256
#define HID 64
#define NC 40
#define NB 196        // destination buckets of 512 nodes (196*512 = 100352)
#define BCAP 10240    // staging capacity per bucket (mean 8192, +22 sigma)
#define CHUNK 2048    // edges per bucket_kernel block
#define NBKB ((EE + CHUNK - 1) / CHUNK)   // 782

typedef unsigned long long ull;

// ---- stage edges into destination buckets; 1 global atomic per (block,bucket) ----
__global__ __launch_bounds__(256) void bucket_kernel(const int* __restrict__ row,
                                                     const int* __restrict__ col,
                                                     const float* __restrict__ w,
                                                     int* __restrict__ bucket_cnt,
                                                     int2* __restrict__ staging) {
    __shared__ int scol[CHUNK];
    __shared__ int2 spay[CHUNK];
    __shared__ int lcnt[NB], lstart[NB];
    const int tid = threadIdx.x;
    const int e0 = blockIdx.x * CHUNK;
    const int nE = min(CHUNK, EE - e0);
    for (int i = tid; i < nE; i += 256) {
        int e = e0 + i;
        int c = col[e];
        scol[i] = c;
        spay[i] = make_int2(((c & 511) << 17) | row[e], __float_as_int(w[e]));
    }
    for (int i = tid; i < NB; i += 256) lcnt[i] = 0;
    __syncthreads();
    for (int i = tid; i < nE; i += 256) atomicAdd(&lcnt[scol[i] >> 9], 1);
    __syncthreads();
    for (int i = tid; i < NB; i += 256) {
        int c = lcnt[i];
        lstart[i] = c ? atomicAdd(&bucket_cnt[i], c) : 0;
        lcnt[i] = 0;
    }
    __syncthreads();
    for (int i = tid; i < nE; i += 256) {
        int b = scol[i] >> 9;
        int slot = lstart[b] + atomicAdd(&lcnt[b], 1);
        if (slot < BCAP) staging[(size_t)b * BCAP + slot] = spay[i];
    }
}

// ---- exclusive scan of bucket counts (one block) ----
__global__ __launch_bounds__(256) void bscan_kernel(int* __restrict__ bucket_cnt,
                                                    int* __restrict__ bucket_base) {
    __shared__ int sd[256];
    int t = threadIdx.x;
    int v = (t < NB) ? min(bucket_cnt[t], BCAP) : 0;
    sd[t] = v;
    __syncthreads();
    for (int off = 1; off < 256; off <<= 1) {
        int u = (t >= off) ? sd[t - off] : 0;
        __syncthreads();
        sd[t] += u;
        __syncthreads();
    }
    if (t < NB) { bucket_base[t] = sd[t] - v; bucket_cnt[t] = v; }
}

// ---- per-bucket: count per dest (LDS), scan, deg->dis, place edges. No global atomics ----
__global__ __launch_bounds__(512) void build_kernel(const int2* __restrict__ staging,
                                                    const int* __restrict__ bucket_cnt,
                                                    const int* __restrict__ bucket_base,
                                                    int2* __restrict__ eme,
                                                    int* __restrict__ basev,
                                                    int* __restrict__ endv,
                                                    float* __restrict__ dis) {
    __shared__ int dcnt[512];
    __shared__ float dsum[512];
    __shared__ int dcur[512];
    __shared__ int sscan[512];
    const int t = threadIdx.x;
    const int b = blockIdx.x;
    const int nE = bucket_cnt[b];
    const int ebase = bucket_base[b];
    const int2* st = staging + (size_t)b * BCAP;
    dcnt[t] = 0; dsum[t] = 0.f;
    __syncthreads();
    for (int i = t; i < nE; i += 512) {
        int2 p = st[i];
        int d = p.x >> 17;
        atomicAdd(&dcnt[d], 1);
        atomicAdd(&dsum[d], __int_as_float(p.y));
    }
    __syncthreads();
    int c = dcnt[t];
    sscan[t] = c;
    __syncthreads();
    for (int off = 1; off < 512; off <<= 1) {
        int u = (t >= off) ? sscan[t - off] : 0;
        __syncthreads();
        sscan[t] += u;
        __syncthreads();
    }
    int gb = ebase + sscan[t] - c;   // exclusive prefix
    int gd = b * 512 + t;
    if (gd < NN) {
        basev[gd] = gb;
        endv[gd] = gb + c;
        dis[gd] = rsqrtf(dsum[t] + 1.0f);
    }
    dcur[t] = gb;
    __syncthreads();
    for (int i = t; i < nE; i += 512) {
        int2 p = st[i];
        int d = p.x >> 17;
        int pos = atomicAdd(&dcur[d], 1);
        eme[pos] = make_int2(p.x & 0x1FFFF, p.y);
    }
}

// ---- rewrite w -> dis[r]*w*dis[n]; wave per node, dis table is L2-resident ----
__global__ __launch_bounds__(256) void norm_kernel(const int* __restrict__ basev,
                                                   const int* __restrict__ endv,
                                                   const float* __restrict__ dis,
                                                   int2* __restrict__ eme) {
    int n = blockIdx.x * 4 + (threadIdx.x >> 6);
    if (n >= NN) return;
    int lane = threadIdx.x & 63;
    int s = basev[n], tEnd = endv[n];
    float dn = dis[n];
    for (int p = s + lane; p < tEnd; p += 64) {
        int2 e = eme[p];
        eme[p] = make_int2(e.x, __float_as_int(dn * __int_as_float(e.y) * dis[e.x]));
    }
}

// ---- GEMM1: xw[N,64](bf16) = x[N,256] @ W1[256,64] ----
__global__ __launch_bounds__(256) void gemm1_kernel(const float* __restrict__ x,
                                                    const float* __restrict__ W,
                                                    __hip_bfloat16* __restrict__ xw) {
    __shared__ float xs[64][65];
    __shared__ float Ws[64][72];
    const int tid = threadIdx.x;
    const int base = blockIdx.x * 64;
    const int ty = tid >> 4;
    const int tx = tid & 15;
    float acc[4][4] = {};

    for (int kb = 0; kb < FIN; kb += 64) {
        for (int v = tid; v < 1024; v += 256) {
            int r = v >> 4, q = v & 15;
            int gr = base + r;
            float4 xv = make_float4(0.f, 0.f, 0.f, 0.f);
            if (gr < NN) xv = *(const float4*)(x + (size_t)gr * FIN + kb + q * 4);
            xs[r][q * 4 + 0] = xv.x; xs[r][q * 4 + 1] = xv.y;
            xs[r][q * 4 + 2] = xv.z; xs[r][q * 4 + 3] = xv.w;
        }
        for (int v = tid; v < 1024; v += 256) {
            int k = v >> 4, q = v & 15;
            float4 wv = *(const float4*)(W + (size_t)(kb + k) * HID + q * 4);
            *(float4*)(&Ws[k][q * 4]) = wv;
        }
        __syncthreads();
#pragma unroll 8
        for (int k = 0; k < 64; k++) {
            float4 wv = *(const float4*)(&Ws[k][tx * 4]);
            float x0 = xs[ty * 4 + 0][k];
            float x1 = xs[ty * 4 + 1][k];
            float x2 = xs[ty * 4 + 2][k];
            float x3 = xs[ty * 4 + 3][k];
            acc[0][0] += x0 * wv.x; acc[0][1] += x0 * wv.y; acc[0][2] += x0 * wv.z; acc[0][3] += x0 * wv.w;
            acc[1][0] += x1 * wv.x; acc[1][1] += x1 * wv.y; acc[1][2] += x1 * wv.z; acc[1][3] += x1 * wv.w;
            acc[2][0] += x2 * wv.x; acc[2][1] += x2 * wv.y; acc[2][2] += x2 * wv.z; acc[2][3] += x2 * wv.w;
            acc[3][0] += x3 * wv.x; acc[3][1] += x3 * wv.y; acc[3][2] += x3 * wv.z; acc[3][3] += x3 * wv.w;
        }
        __syncthreads();
    }
#pragma unroll
    for (int i = 0; i < 4; i++) {
        int gr = base + ty * 4 + i;
        if (gr < NN) {
            union { __hip_bfloat16 h[4]; uint2 u; } pkd;
            pkd.h[0] = __float2bfloat16(acc[i][0]);
            pkd.h[1] = __float2bfloat16(acc[i][1]);
            pkd.h[2] = __float2bfloat16(acc[i][2]);
            pkd.h[3] = __float2bfloat16(acc[i][3]);
            *(uint2*)(xw + (size_t)gr * HID + tx * 4) = pkd.u;
        }
    }
}

// ---- gather1: h[n,f] = relu(sum norm*xw[r,f] + dis^2*xw[n,f] + b1[f]) ----
__global__ __launch_bounds__(256) void gather1_kernel(const int* __restrict__ basev,
                                                      const int* __restrict__ endv,
                                                      const ull* __restrict__ eme,
                                                      const __hip_bfloat16* __restrict__ xw,
                                                      const float* __restrict__ dis,
                                                      const float* __restrict__ b,
                                                      float* __restrict__ h) {
    int n = blockIdx.x * 4 + (threadIdx.x >> 6);
    if (n >= NN) return;
    int lane = threadIdx.x & 63;
    int s = basev[n], t = endv[n];
    float acc = 0.f;
    int p = s;
    for (; p + 8 <= t; p += 8) {
        ull q[8];
#pragma unroll
        for (int j = 0; j < 8; j++) q[j] = __builtin_nontemporal_load(&eme[p + j]);
        float v[8];
#pragma unroll
        for (int j = 0; j < 8; j++)
            v[j] = __bfloat162float(xw[(size_t)(unsigned)(q[j] & 0xFFFFFFFFu) * HID + lane]);
#pragma unroll
        for (int j = 0; j < 8; j++)
            acc += __int_as_float((int)(q[j] >> 32)) * v[j];
    }
    for (; p + 4 <= t; p += 4) {
        ull q[4];
#pragma unroll
        for (int j = 0; j < 4; j++) q[j] = __builtin_nontemporal_load(&eme[p + j]);
#pragma unroll
        for (int j = 0; j < 4; j++)
            acc += __int_as_float((int)(q[j] >> 32)) *
                   __bfloat162float(xw[(size_t)(unsigned)(q[j] & 0xFFFFFFFFu) * HID + lane]);
    }
    for (; p < t; ++p) {
        ull q = __builtin_nontemporal_load(&eme[p]);
        acc += __int_as_float((int)(q >> 32)) *
               __bfloat162float(xw[(size_t)(unsigned)(q & 0xFFFFFFFFu) * HID + lane]);
    }
    float d = dis[n];
    float v = acc + d * d * __bfloat162float(xw[(size_t)n * HID + lane]) + b[lane];
    h[(size_t)n * HID + lane] = fmaxf(v, 0.f);
}

// ---- GEMM2: hw2[N,40](bf16) = h[N,64] @ W2[64,40] ----
__global__ __launch_bounds__(256) void gemm2_kernel(const float* __restrict__ h,
                                                    const float* __restrict__ W,
                                                    __hip_bfloat16* __restrict__ hw) {
    __shared__ float hs[64][65];
    __shared__ float Ws[HID * NC];
    const int tid = threadIdx.x;
    const int base = blockIdx.x * 64;
    for (int v = tid; v < 1024; v += 256) {
        int r = v >> 4, q = v & 15;
        int gr = base + r;
        float4 hv = make_float4(0.f, 0.f, 0.f, 0.f);
        if (gr < NN) hv = *(const float4*)(h + (size_t)gr * HID + q * 4);
        hs[r][q * 4 + 0] = hv.x; hs[r][q * 4 + 1] = hv.y;
        hs[r][q * 4 + 2] = hv.z; hs[r][q * 4 + 3] = hv.w;
    }
    for (int v = tid; v < HID * NC; v += 256) Ws[v] = W[v];
    __syncthreads();
    const int tx = tid & 7;
    const int ty = tid >> 3;
    float acc[2][5] = {};
#pragma unroll 8
    for (int k = 0; k < HID; k++) {
        float h0 = hs[ty * 2 + 0][k];
        float h1 = hs[ty * 2 + 1][k];
        const float* wr = &Ws[k * NC + tx * 5];
        float w0 = wr[0], w1 = wr[1], w2 = wr[2], w3 = wr[3], w4 = wr[4];
        acc[0][0] += h0 * w0; acc[0][1] += h0 * w1; acc[0][2] += h0 * w2;
        acc[0][3] += h0 * w3; acc[0][4] += h0 * w4;
        acc[1][0] += h1 * w0; acc[1][1] += h1 * w1; acc[1][2] += h1 * w2;
        acc[1][3] += h1 * w3; acc[1][4] += h1 * w4;
    }
#pragma unroll
    for (int i = 0; i < 2; i++) {
        int gr = base + ty * 2 + i;
        if (gr < NN) {
#pragma unroll
            for (int c = 0; c < 5; c++)
                hw[(size_t)gr * NC + tx * 5 + c] = __float2bfloat16(acc[i][c]);
        }
    }
}

// ---- gather2 + final: out = agg + dis^2*hw + b2 ; log_softmax fused ----
__global__ __launch_bounds__(256) void gather2_kernel(const int* __restrict__ basev,
                                                      const int* __restrict__ endv,
                                                      const ull* __restrict__ eme,
                                                      const __hip_bfloat16* __restrict__ hw,
                                                      const float* __restrict__ dis,
                                                      const float* __restrict__ b,
                                                      float* __restrict__ out) {
    int n = blockIdx.x * 4 + (threadIdx.x >> 6);
    if (n >= NN) return;
    int lane = threadIdx.x & 63;
    bool act = lane < NC;
    int lidx = act ? lane : 0;
    int s = basev[n], t = endv[n];
    float acc = 0.f;
    int p = s;
    for (; p + 8 <= t; p += 8) {
        ull q[8];
#pragma unroll
        for (int j = 0; j < 8; j++) q[j] = __builtin_nontemporal_load(&eme[p + j]);
        float v[8];
#pragma unroll
        for (int j = 0; j < 8; j++)
            v[j] = __bfloat162float(hw[(size_t)(unsigned)(q[j] & 0xFFFFFFFFu) * NC + lidx]);
#pragma unroll
        for (int j = 0; j < 8; j++)
            acc += __int_as_float((int)(q[j] >> 32)) * v[j];
    }
    for (; p + 4 <= t; p += 4) {
        ull q[4];
#pragma unroll
        for (int j = 0; j < 4; j++) q[j] = __builtin_nontemporal_load(&eme[p + j]);
#pragma unroll
        for (int j = 0; j < 4; j++)
            acc += __int_as_float((int)(q[j] >> 32)) *
                   __bfloat162float(hw[(size_t)(unsigned)(q[j] & 0xFFFFFFFFu) * NC + lidx]);
    }
    for (; p < t; ++p) {
        ull q = __builtin_nontemporal_load(&eme[p]);
        acc += __int_as_float((int)(q >> 32)) *
               __bfloat162float(hw[(size_t)(unsigned)(q & 0xFFFFFFFFu) * NC + lidx]);
    }
    float val = 0.f, v = -INFINITY;
    if (act) {
        float d = dis[n];
        val = acc + d * d * __bfloat162float(hw[(size_t)n * NC + lane]) + b[lane];
        v = val;
    }
    float m = v;
#pragma unroll
    for (int off = 32; off; off >>= 1) m = fmaxf(m, __shfl_xor(m, off));
    float e = act ? expf(val - m) : 0.f;
    float sum = e;
#pragma unroll
    for (int off = 32; off; off >>= 1) sum += __shfl_xor(sum, off);
    float lse = m + logf(sum);
    if (act) {
        size_t idx = (size_t)n * NC + lane;
        out[idx] = val;
        out[(size_t)NN * NC + idx] = val - lse;
    }
}

extern "C" void kernel_launch(void* const* d_in, const int* in_sizes, int n_in,
                              void* d_out, int out_size, void* d_ws, size_t ws_size,
                              hipStream_t stream) {
    const float* x    = (const float*)d_in[0];
    const int*   eidx = (const int*)d_in[1];
    const float* ew   = (const float*)d_in[2];
    const float* W1   = (const float*)d_in[3];
    const float* b1   = (const float*)d_in[4];
    const float* W2   = (const float*)d_in[5];
    const float* b2   = (const float*)d_in[6];
    float* out = (float*)d_out;

    const int* row = eidx;
    const int* col = eidx + EE;

    char* ws = (char*)d_ws;
    int*   bucket_cnt  = (int*)ws;               ws += 256 * 4;
    int*   bucket_base = (int*)ws;               ws += 256 * 4;
    float* dis    = (float*)ws;                  ws += NN * 4;
    int*   basev  = (int*)ws;                    ws += NN * 4;
    int*   endv   = (int*)ws;                    ws += NN * 4;
    int2*  eme    = (int2*)ws;                   ws += (size_t)EE * 8;
    __hip_bfloat16* xw = (__hip_bfloat16*)ws;    ws += (size_t)NN * HID * 2;
    // staging (16.06 MB) and h (25.6 MB) are never live simultaneously: union them
    char* unionp = ws;                           ws += (size_t)NN * HID * 4;
    int2*  staging = (int2*)unionp;              // NB*BCAP*8 = 16.06 MB <= 25.6 MB
    float* h       = (float*)unionp;
    __hip_bfloat16* hw2 = (__hip_bfloat16*)ws;   ws += (size_t)NN * NC * 2;

    hipMemsetAsync(bucket_cnt, 0, 256 * 4, stream);

    bucket_kernel<<<NBKB, 256, 0, stream>>>(row, col, ew, bucket_cnt, staging);
    bscan_kernel<<<1, 256, 0, stream>>>(bucket_cnt, bucket_base);
    build_kernel<<<NB, 512, 0, stream>>>(staging, bucket_cnt, bucket_base,
                                         eme, basev, endv, dis);
    norm_kernel<<<(NN + 3) / 4, 256, 0, stream>>>(basev, endv, dis, eme);
    gemm1_kernel<<<(NN + 63) / 64, 256, 0, stream>>>(x, W1, xw);
    gather1_kernel<<<(NN + 3) / 4, 256, 0, stream>>>(basev, endv, (const ull*)eme,
                                                     xw, dis, b1, h);
    gemm2_kernel<<<(NN + 63) / 64, 256, 0, stream>>>(h, W2, hw2);
    gather2_kernel<<<(NN + 3) / 4, 256, 0, stream>>>(basev, endv, (const ull*)eme,
                                                     hw2, dis, b2, out);
}